// Round 6
// baseline (77.076 us; speedup 1.0000x reference)
//
#include <hip/hip_runtime.h>
#include <hip/hip_bf16.h>
#include <math.h>

#define BB 8
#define FF 16
#define DD 256
#define HH 64
#define WW 64

typedef short bf16x8 __attribute__((ext_vector_type(8)));
typedef float f32x4 __attribute__((ext_vector_type(4)));

__device__ inline ushort f2bf(float f) {
    union { float f; unsigned u; } v; v.f = f;
    unsigned r = v.u + 0x7FFFu + ((v.u >> 16) & 1u);   // RNE
    return (ushort)(r >> 16);
}

// ---------------------------------------------------------------------------
// Kernel 0: cast x fp32 -> bf16, transpose to xb[b][r][c][i] (i innermost)
// ---------------------------------------------------------------------------
__global__ __launch_bounds__(256) void cast_x(
    const float* __restrict__ x,   // (B, D, 64, 64)
    ushort* __restrict__ xb)       // (B, 64, 64, D)
{
    __shared__ ushort ls[64][258];
    const int r = blockIdx.x, b = blockIdx.y, t = threadIdx.x;

    const int c4 = (t & 15) * 4;
    const int ig = t >> 4;
#pragma unroll
    for (int j = 0; j < 16; ++j) {
        const int i = ig * 16 + j;
        const float4 xv = *reinterpret_cast<const float4*>(
            x + (((size_t)(b * DD + i) * HH) + r) * WW + c4);
        ls[c4 + 0][i] = f2bf(xv.x);
        ls[c4 + 1][i] = f2bf(xv.y);
        ls[c4 + 2][i] = f2bf(xv.z);
        ls[c4 + 3][i] = f2bf(xv.w);
    }
    __syncthreads();

    const int i2 = t & 127;
    const int ch = t >> 7;
#pragma unroll
    for (int cl = 0; cl < 32; ++cl) {
        const int c = ch * 32 + cl;
        const unsigned u = (unsigned)ls[c][2 * i2] | ((unsigned)ls[c][2 * i2 + 1] << 16);
        *reinterpret_cast<unsigned*>(xb + (((size_t)(b * HH + r) * WW) + c) * DD + 2 * i2) = u;
    }
}

// ---------------------------------------------------------------------------
// Kernel 1: filters for ALL batches in one pass over bank_weight.
// Ak[b][tap][i/8][o][8] bf16  (coalesced A-fragment loads in conv)
// ---------------------------------------------------------------------------
__global__ __launch_bounds__(256) void prep_filter(
    const float* __restrict__ bank_request,   // (B, F)
    const float* __restrict__ style,          // (B, 1, D, 1, 1)
    const float* __restrict__ bank_weight,    // (F, D, D, 3, 3)
    ushort* __restrict__ Ak)                  // (B, 9, 32, 256, 8)
{
    const int o = blockIdx.x;
    const int i = threadIdx.x;

    __shared__ float wsm[BB][FF];
    __shared__ float red[4][BB];
    __shared__ float nrm[BB];

    if (i < BB) {
        float v[FF];
        float m = -1e30f;
#pragma unroll
        for (int f = 0; f < FF; ++f) {
            v[f] = bank_request[i * FF + f];
            m = fmaxf(m, v[f]);
        }
        float s = 0.f;
#pragma unroll
        for (int f = 0; f < FF; ++f) { v[f] = __expf(v[f] - m); s += v[f]; }
        const float inv = 1.0f / s;
#pragma unroll
        for (int f = 0; f < FF; ++f) wsm[i][f] = v[f] * inv;
    }
    __syncthreads();

    float acc9[BB][9];
#pragma unroll
    for (int b = 0; b < BB; ++b)
#pragma unroll
        for (int j = 0; j < 9; ++j) acc9[b][j] = 0.f;

    float pre[2][9];
#pragma unroll
    for (int s = 0; s < 2; ++s) {
        const float* p = bank_weight + ((size_t)(s * DD + o) * DD + i) * 9;
#pragma unroll
        for (int j = 0; j < 9; ++j) pre[s][j] = p[j];
    }
#pragma unroll
    for (int f = 0; f < FF; ++f) {
        const int sl = f & 1;
        float cur[9];
#pragma unroll
        for (int j = 0; j < 9; ++j) cur[j] = pre[sl][j];
        if (f + 2 < FF) {
            const float* p = bank_weight + ((size_t)((f + 2) * DD + o) * DD + i) * 9;
#pragma unroll
            for (int j = 0; j < 9; ++j) pre[sl][j] = p[j];
        }
#pragma unroll
        for (int b = 0; b < BB; ++b) {
            const float wf = wsm[b][f];
#pragma unroll
            for (int j = 0; j < 9; ++j) acc9[b][j] = fmaf(wf, cur[j], acc9[b][j]);
        }
    }

    float ss[BB];
#pragma unroll
    for (int b = 0; b < BB; ++b) {
        const float sm = 1.0f + style[b * DD + i];
        float t = 0.f;
#pragma unroll
        for (int j = 0; j < 9; ++j) {
            acc9[b][j] *= sm;
            t = fmaf(acc9[b][j], acc9[b][j], t);
        }
        ss[b] = t;
    }

    const int wave = i >> 6, lane = i & 63;
#pragma unroll
    for (int b = 0; b < BB; ++b) {
        float tv = ss[b];
#pragma unroll
        for (int off = 32; off > 0; off >>= 1) tv += __shfl_down(tv, off, 64);
        if (lane == 0) red[wave][b] = tv;
    }
    __syncthreads();
    if (i < BB)
        nrm[i] = rsqrtf(red[0][i] + red[1][i] + red[2][i] + red[3][i] + 1e-8f);
    __syncthreads();

    const int ib = i >> 3, e = i & 7;
#pragma unroll
    for (int b = 0; b < BB; ++b) {
        const float nb = nrm[b];
#pragma unroll
        for (int j = 0; j < 9; ++j) {
            const size_t idx = ((((size_t)(b * 9 + j) * 32 + ib) * DD) + o) * 8 + e;
            Ak[idx] = f2bf(acc9[b][j] * nb);
        }
    }
}

// ---------------------------------------------------------------------------
// Kernel 2: implicit-GEMM conv, MFMA 16x16x32 bf16.
// grid = 512 (1D, XCD-swizzled), block = 512 (8 waves).
// Block tile: 128 o x (2 rows x 64 cols). Wave: 64 o x 32 px (4x2 frags).
// 2 blocks/CU (42 KB LDS, <=128 VGPR) -> 4 waves/SIMD for latency hiding.
// XCD swizzle: all 32 rowpair-blocks of one (b,ot) group on one XCD so the
// shared Ak slice stays L2-resident per-kc.
// ---------------------------------------------------------------------------
#define XROWS 4
#define XCELLS 66
#define XCELLB 80
#define XBUF (XROWS * XCELLS * XCELLB)   // 21120 B

__global__ __launch_bounds__(512, 4) void conv_mfma(
    const ushort* __restrict__ xb,   // (B, 64, 64, D) bf16
    const ushort* __restrict__ Ak,   // (B, 9, 32, 256, 8) bf16
    float* __restrict__ out)         // (B, D, 64, 64) fp32
{
    __shared__ __align__(16) char xs[2 * XBUF];   // 42240 B

    // wgid = (G&7) + 8*rg + 256*(G>>3), G = ot + 2*b
    const int wg = blockIdx.x;
    const int xcd = wg & 7;
    const int rem = wg >> 3;
    const int rg = rem & 31;
    const int Ghi = rem >> 5;            // 0..1
    const int G = xcd + 8 * Ghi;         // 0..15
    const int ot = G & 1, b = G >> 1;

    const int r0 = rg * 2, o0 = ot * 128;
    const int t = threadIdx.x;
    const int w = t >> 6, l = t & 63;
    const int wm = w >> 2;          // o half (0,1)
    const int wn = (w >> 1) & 1;    // row (0,1)
    const int wp = w & 1;           // col half (0,1)
    const int lo = l & 15, lhi = l >> 4;

    // staging: 4 rows * 66 cells * 4 q = 1056 16B chunks over 512 threads
    const ushort* sg_ptr[3];
    int sg_lds[3];
    bool sg_ok[3];
#pragma unroll
    for (int s = 0; s < 3; ++s) {
        const int idx = t + s * 512;
        const bool active = (s < 2) || (t < 32);
        const int row = idx / (XCELLS * 4);
        const int rem2 = idx - row * (XCELLS * 4);
        const int cell = rem2 >> 2;
        const int q = rem2 & 3;
        const int gr = r0 - 1 + row;
        const int gc = cell - 1;
        sg_ok[s] = active && ((unsigned)gr < 64u) && ((unsigned)gc < 64u);
        sg_ptr[s] = xb + (((size_t)(b * HH + (gr & 63)) * WW) + (gc & 63)) * DD + q * 8;
        sg_lds[s] = (row * XCELLS + cell) * XCELLB + q * 16;
    }
    const bool sg_act2 = (t < 32);

    f32x4 acc[4][2];
#pragma unroll
    for (int a = 0; a < 4; ++a)
#pragma unroll
        for (int c = 0; c < 2; ++c)
#pragma unroll
            for (int j = 0; j < 4; ++j) acc[a][c][j] = 0.f;

    const int obase = o0 + wm * 64 + lo;
    const int bLane = (wp * 32 + lo) * XCELLB + lhi * 16;

    bf16x8 vr[3];
    bf16x8 aF[3][4], bF[2][2];

#define LDA(tp, sl, aB)  do {                                                  \
        const ushort* ap_ = (aB) + (size_t)(tp) * 65536;                       \
        aF[sl][0] = *reinterpret_cast<const bf16x8*>(ap_);                     \
        aF[sl][1] = *reinterpret_cast<const bf16x8*>(ap_ + 128);               \
        aF[sl][2] = *reinterpret_cast<const bf16x8*>(ap_ + 256);               \
        aF[sl][3] = *reinterpret_cast<const bf16x8*>(ap_ + 384);               \
    } while (0)

#define LDB(tp, sl, bufc)  do {                                                \
        const int dr_ = (tp) / 3, dc_ = (tp) % 3;                              \
        const char* bb_ = (bufc) + ((wn + dr_) * XCELLS + dc_) * XCELLB;       \
        bF[sl][0] = *reinterpret_cast<const bf16x8*>(bb_);                     \
        bF[sl][1] = *reinterpret_cast<const bf16x8*>(bb_ + 16 * XCELLB);       \
    } while (0)

    // prologue: stage chunk 0 into buffer 0
#pragma unroll
    for (int s = 0; s < 3; ++s) {
        if (s < 2 || sg_act2) {
            bf16x8 v = {0, 0, 0, 0, 0, 0, 0, 0};
            if (sg_ok[s]) v = *reinterpret_cast<const bf16x8*>(sg_ptr[s]);
            *reinterpret_cast<bf16x8*>(xs + sg_lds[s]) = v;
        }
    }
    __syncthreads();

    for (int kc = 0; kc < 8; ++kc) {
        const int cur = kc & 1;

        // issue next chunk's global loads (hide under 9-tap compute)
        if (kc < 7) {
            const int ioff = (kc + 1) * 32;
#pragma unroll
            for (int s = 0; s < 3; ++s) {
                bf16x8 v = {0, 0, 0, 0, 0, 0, 0, 0};
                if (sg_ok[s]) v = *reinterpret_cast<const bf16x8*>(sg_ptr[s] + ioff);
                vr[s] = v;
            }
        }

        const char* bufc = xs + cur * XBUF + bLane;
        const int ib = kc * 4 + lhi;
        const ushort* aBase = Ak + (((size_t)b * 9 * 32 + ib) * DD + obase) * 8;

        LDA(0, 0, aBase);
        LDA(1, 1, aBase);
        LDB(0, 0, bufc);
#pragma unroll
        for (int tap = 0; tap < 9; ++tap) {
            const int as = tap % 3;
            if (tap + 2 <= 8) LDA(tap + 2, (tap + 2) % 3, aBase);
            if (tap < 8) LDB(tap + 1, (tap + 1) & 1, bufc);
            const int bs = tap & 1;
            __builtin_amdgcn_s_setprio(1);
#pragma unroll
            for (int fm = 0; fm < 4; ++fm)
#pragma unroll
                for (int fn = 0; fn < 2; ++fn)
                    acc[fm][fn] = __builtin_amdgcn_mfma_f32_16x16x32_bf16(
                        aF[as][fm], bF[bs][fn], acc[fm][fn], 0, 0, 0);
            __builtin_amdgcn_s_setprio(0);
        }

        // write staged chunk to the other buffer
        if (kc < 7) {
            char* dstb = xs + (cur ^ 1) * XBUF;
#pragma unroll
            for (int s = 0; s < 3; ++s)
                if (s < 2 || sg_act2)
                    *reinterpret_cast<bf16x8*>(dstb + sg_lds[s]) = vr[s];
        }
        __syncthreads();
    }
#undef LDA
#undef LDB

    // epilogue: C/D layout col=lane&15 (px), row=(lane>>4)*4+reg (o)
    const int r_out = r0 + wn;
#pragma unroll
    for (int fm = 0; fm < 4; ++fm) {
#pragma unroll
        for (int fn = 0; fn < 2; ++fn) {
            const int oo = o0 + wm * 64 + fm * 16 + lhi * 4;
            const int cc = wp * 32 + fn * 16 + lo;
            float* op = out + (((size_t)(b * DD + oo) * HH) + r_out) * WW + cc;
#pragma unroll
            for (int j = 0; j < 4; ++j) op[(size_t)j * HH * WW] = acc[fm][fn][j];
        }
    }
}

extern "C" void kernel_launch(void* const* d_in, const int* in_sizes, int n_in,
                              void* d_out, int out_size, void* d_ws, size_t ws_size,
                              hipStream_t stream) {
    const float* x            = (const float*)d_in[0];  // (8,256,64,64)
    const float* bank_request = (const float*)d_in[1];  // (8,16)
    const float* style        = (const float*)d_in[2];  // (8,1,256,1,1)
    const float* bank_weight  = (const float*)d_in[3];  // (16,256,256,3,3)
    float* out = (float*)d_out;                         // (8,256,64,64)

    ushort* Ak = (ushort*)d_ws;                         // 8*9*32*256*8 elems
    ushort* xb = Ak + (size_t)8 * 9 * 32 * 256 * 8;     // 8*64*64*256 elems

    cast_x<<<dim3(HH, BB), 256, 0, stream>>>(x, xb);
    prep_filter<<<dim3(DD), 256, 0, stream>>>(bank_request, style, bank_weight, Ak);
    conv_mfma<<<dim3(512), 512, 0, stream>>>(xb, Ak, out);
}

// Round 7
// 68.258 us; speedup vs baseline: 1.1292x; 1.1292x over previous
//
#include <hip/hip_runtime.h>
#include <hip/hip_bf16.h>
#include <math.h>

#define BB 8
#define FF 16
#define DD 256
#define HH 64
#define WW 64

typedef short bf16x8 __attribute__((ext_vector_type(8)));
typedef float f32x4 __attribute__((ext_vector_type(4)));

__device__ inline ushort f2bf(float f) {
    union { float f; unsigned u; } v; v.f = f;
    unsigned r = v.u + 0x7FFFu + ((v.u >> 16) & 1u);   // RNE
    return (ushort)(r >> 16);
}

// ---------------------------------------------------------------------------
// Kernel 0: cast x fp32 -> bf16, transpose to xb[b][r][c][i] (i innermost)
// ---------------------------------------------------------------------------
__global__ __launch_bounds__(256) void cast_x(
    const float* __restrict__ x,   // (B, D, 64, 64)
    ushort* __restrict__ xb)       // (B, 64, 64, D)
{
    __shared__ ushort ls[64][258];
    const int r = blockIdx.x, b = blockIdx.y, t = threadIdx.x;

    const int c4 = (t & 15) * 4;
    const int ig = t >> 4;
#pragma unroll
    for (int j = 0; j < 16; ++j) {
        const int i = ig * 16 + j;
        const float4 xv = *reinterpret_cast<const float4*>(
            x + (((size_t)(b * DD + i) * HH) + r) * WW + c4);
        ls[c4 + 0][i] = f2bf(xv.x);
        ls[c4 + 1][i] = f2bf(xv.y);
        ls[c4 + 2][i] = f2bf(xv.z);
        ls[c4 + 3][i] = f2bf(xv.w);
    }
    __syncthreads();

    const int i2 = t & 127;
    const int ch = t >> 7;
#pragma unroll
    for (int cl = 0; cl < 32; ++cl) {
        const int c = ch * 32 + cl;
        const unsigned u = (unsigned)ls[c][2 * i2] | ((unsigned)ls[c][2 * i2 + 1] << 16);
        *reinterpret_cast<unsigned*>(xb + (((size_t)(b * HH + r) * WW) + c) * DD + 2 * i2) = u;
    }
}

// ---------------------------------------------------------------------------
// Kernel 1: filters for ALL batches in one pass over bank_weight.
// Ak[b][tap][i/8][o][8] bf16  (coalesced A-fragment loads in conv)
// ---------------------------------------------------------------------------
__global__ __launch_bounds__(256) void prep_filter(
    const float* __restrict__ bank_request,   // (B, F)
    const float* __restrict__ style,          // (B, 1, D, 1, 1)
    const float* __restrict__ bank_weight,    // (F, D, D, 3, 3)
    ushort* __restrict__ Ak)                  // (B, 9, 32, 256, 8)
{
    const int o = blockIdx.x;
    const int i = threadIdx.x;

    __shared__ float wsm[BB][FF];
    __shared__ float red[4][BB];
    __shared__ float nrm[BB];

    if (i < BB) {
        float v[FF];
        float m = -1e30f;
#pragma unroll
        for (int f = 0; f < FF; ++f) {
            v[f] = bank_request[i * FF + f];
            m = fmaxf(m, v[f]);
        }
        float s = 0.f;
#pragma unroll
        for (int f = 0; f < FF; ++f) { v[f] = __expf(v[f] - m); s += v[f]; }
        const float inv = 1.0f / s;
#pragma unroll
        for (int f = 0; f < FF; ++f) wsm[i][f] = v[f] * inv;
    }
    __syncthreads();

    float acc9[BB][9];
#pragma unroll
    for (int b = 0; b < BB; ++b)
#pragma unroll
        for (int j = 0; j < 9; ++j) acc9[b][j] = 0.f;

    float pre[2][9];
#pragma unroll
    for (int s = 0; s < 2; ++s) {
        const float* p = bank_weight + ((size_t)(s * DD + o) * DD + i) * 9;
#pragma unroll
        for (int j = 0; j < 9; ++j) pre[s][j] = p[j];
    }
#pragma unroll
    for (int f = 0; f < FF; ++f) {
        const int sl = f & 1;
        float cur[9];
#pragma unroll
        for (int j = 0; j < 9; ++j) cur[j] = pre[sl][j];
        if (f + 2 < FF) {
            const float* p = bank_weight + ((size_t)((f + 2) * DD + o) * DD + i) * 9;
#pragma unroll
            for (int j = 0; j < 9; ++j) pre[sl][j] = p[j];
        }
#pragma unroll
        for (int b = 0; b < BB; ++b) {
            const float wf = wsm[b][f];
#pragma unroll
            for (int j = 0; j < 9; ++j) acc9[b][j] = fmaf(wf, cur[j], acc9[b][j]);
        }
    }

    float ss[BB];
#pragma unroll
    for (int b = 0; b < BB; ++b) {
        const float sm = 1.0f + style[b * DD + i];
        float t = 0.f;
#pragma unroll
        for (int j = 0; j < 9; ++j) {
            acc9[b][j] *= sm;
            t = fmaf(acc9[b][j], acc9[b][j], t);
        }
        ss[b] = t;
    }

    const int wave = i >> 6, lane = i & 63;
#pragma unroll
    for (int b = 0; b < BB; ++b) {
        float tv = ss[b];
#pragma unroll
        for (int off = 32; off > 0; off >>= 1) tv += __shfl_down(tv, off, 64);
        if (lane == 0) red[wave][b] = tv;
    }
    __syncthreads();
    if (i < BB)
        nrm[i] = rsqrtf(red[0][i] + red[1][i] + red[2][i] + red[3][i] + 1e-8f);
    __syncthreads();

    const int ib = i >> 3, e = i & 7;
#pragma unroll
    for (int b = 0; b < BB; ++b) {
        const float nb = nrm[b];
#pragma unroll
        for (int j = 0; j < 9; ++j) {
            const size_t idx = ((((size_t)(b * 9 + j) * 32 + ib) * DD) + o) * 8 + e;
            Ak[idx] = f2bf(acc9[b][j] * nb);
        }
    }
}

// ---------------------------------------------------------------------------
// Kernel 2: implicit-GEMM conv, MFMA 16x16x32 bf16.
// grid = 512 (XCD-swizzled), block = 512 (8 waves).
// Block tile: 128 o x (2 rows x 64 cols). Wave: 32 o x 64 px (fm=2, fn=4):
// A-traffic 256 B/MFMA (L2-friendly) at 2 blocks/CU (4 waves/SIMD).
// ---------------------------------------------------------------------------
#define XROWS 4
#define XCELLS 66
#define XCELLB 80
#define XBUF (XROWS * XCELLS * XCELLB)   // 21120 B

__global__ __launch_bounds__(512, 4) void conv_mfma(
    const ushort* __restrict__ xb,   // (B, 64, 64, D) bf16
    const ushort* __restrict__ Ak,   // (B, 9, 32, 256, 8) bf16
    float* __restrict__ out)         // (B, D, 64, 64) fp32
{
    __shared__ __align__(16) char xs[2 * XBUF];   // 42240 B

    // wgid = (G&7) + 8*rg + 256*(G>>3), G = ot + 2*b  -> each XCD hosts 2 groups
    const int wg = blockIdx.x;
    const int xcd = wg & 7;
    const int rem = wg >> 3;
    const int rg = rem & 31;
    const int Ghi = rem >> 5;            // 0..1
    const int G = xcd + 8 * Ghi;         // 0..15
    const int ot = G & 1, b = G >> 1;

    const int r0 = rg * 2, o0 = ot * 128;
    const int t = threadIdx.x;
    const int w = t >> 6, l = t & 63;
    const int wm = w & 3;           // o quarter (0..3) -> 32 o per wave
    const int wn = w >> 2;          // row (0,1)
    const int lo = l & 15, lhi = l >> 4;

    // staging: 4 rows * 66 cells * 4 q = 1056 16B chunks over 512 threads
    const ushort* sg_ptr[3];
    int sg_lds[3];
    bool sg_ok[3];
#pragma unroll
    for (int s = 0; s < 3; ++s) {
        const int idx = t + s * 512;
        const bool active = (s < 2) || (t < 32);
        const int row = idx / (XCELLS * 4);
        const int rem2 = idx - row * (XCELLS * 4);
        const int cell = rem2 >> 2;
        const int q = rem2 & 3;
        const int gr = r0 - 1 + row;
        const int gc = cell - 1;
        sg_ok[s] = active && ((unsigned)gr < 64u) && ((unsigned)gc < 64u);
        sg_ptr[s] = xb + (((size_t)(b * HH + (gr & 63)) * WW) + (gc & 63)) * DD + q * 8;
        sg_lds[s] = (row * XCELLS + cell) * XCELLB + q * 16;
    }
    const bool sg_act2 = (t < 32);

    f32x4 acc[2][4];
#pragma unroll
    for (int a = 0; a < 2; ++a)
#pragma unroll
        for (int c = 0; c < 4; ++c)
#pragma unroll
            for (int j = 0; j < 4; ++j) acc[a][c][j] = 0.f;

    const int obase = o0 + wm * 32 + lo;
    const int bLane = lo * XCELLB + lhi * 16;

    bf16x8 vr[3];
    bf16x8 aF[3][2], bF[2][4];

#define LDA(tp, sl, aB)  do {                                                  \
        const ushort* ap_ = (aB) + (size_t)(tp) * 65536;                       \
        aF[sl][0] = *reinterpret_cast<const bf16x8*>(ap_);                     \
        aF[sl][1] = *reinterpret_cast<const bf16x8*>(ap_ + 128);               \
    } while (0)

#define LDB(tp, sl, bufc)  do {                                                \
        const int dr_ = (tp) / 3, dc_ = (tp) % 3;                              \
        const char* bb_ = (bufc) + ((wn + dr_) * XCELLS + dc_) * XCELLB;       \
        bF[sl][0] = *reinterpret_cast<const bf16x8*>(bb_);                     \
        bF[sl][1] = *reinterpret_cast<const bf16x8*>(bb_ + 16 * XCELLB);       \
        bF[sl][2] = *reinterpret_cast<const bf16x8*>(bb_ + 32 * XCELLB);       \
        bF[sl][3] = *reinterpret_cast<const bf16x8*>(bb_ + 48 * XCELLB);       \
    } while (0)

    // prologue: stage chunk 0 into buffer 0
#pragma unroll
    for (int s = 0; s < 3; ++s) {
        if (s < 2 || sg_act2) {
            bf16x8 v = {0, 0, 0, 0, 0, 0, 0, 0};
            if (sg_ok[s]) v = *reinterpret_cast<const bf16x8*>(sg_ptr[s]);
            *reinterpret_cast<bf16x8*>(xs + sg_lds[s]) = v;
        }
    }
    __syncthreads();

    for (int kc = 0; kc < 8; ++kc) {
        const int cur = kc & 1;

        // issue next chunk's global loads (hide under 9-tap compute)
        if (kc < 7) {
            const int ioff = (kc + 1) * 32;
#pragma unroll
            for (int s = 0; s < 3; ++s) {
                bf16x8 v = {0, 0, 0, 0, 0, 0, 0, 0};
                if (sg_ok[s]) v = *reinterpret_cast<const bf16x8*>(sg_ptr[s] + ioff);
                vr[s] = v;
            }
        }

        const char* bufc = xs + cur * XBUF + bLane;
        const int ib = kc * 4 + lhi;
        const ushort* aBase = Ak + (((size_t)b * 9 * 32 + ib) * DD + obase) * 8;

        LDA(0, 0, aBase);
        LDA(1, 1, aBase);
        LDB(0, 0, bufc);
#pragma unroll
        for (int tap = 0; tap < 9; ++tap) {
            const int as = tap % 3;
            if (tap + 2 <= 8) LDA(tap + 2, (tap + 2) % 3, aBase);
            if (tap < 8) LDB(tap + 1, (tap + 1) & 1, bufc);
            const int bs = tap & 1;
            __builtin_amdgcn_s_setprio(1);
#pragma unroll
            for (int fm = 0; fm < 2; ++fm)
#pragma unroll
                for (int fn = 0; fn < 4; ++fn)
                    acc[fm][fn] = __builtin_amdgcn_mfma_f32_16x16x32_bf16(
                        aF[as][fm], bF[bs][fn], acc[fm][fn], 0, 0, 0);
            __builtin_amdgcn_s_setprio(0);
        }

        // write staged chunk to the other buffer
        if (kc < 7) {
            char* dstb = xs + (cur ^ 1) * XBUF;
#pragma unroll
            for (int s = 0; s < 3; ++s)
                if (s < 2 || sg_act2)
                    *reinterpret_cast<bf16x8*>(dstb + sg_lds[s]) = vr[s];
        }
        __syncthreads();
    }
#undef LDA
#undef LDB

    // epilogue: C/D layout col=lane&15 (px), row=(lane>>4)*4+reg (o)
    const int r_out = r0 + wn;
#pragma unroll
    for (int fm = 0; fm < 2; ++fm) {
#pragma unroll
        for (int fn = 0; fn < 4; ++fn) {
            const int oo = o0 + wm * 32 + fm * 16 + lhi * 4;
            const int cc = fn * 16 + lo;
            float* op = out + (((size_t)(b * DD + oo) * HH) + r_out) * WW + cc;
#pragma unroll
            for (int j = 0; j < 4; ++j) op[(size_t)j * HH * WW] = acc[fm][fn][j];
        }
    }
}

extern "C" void kernel_launch(void* const* d_in, const int* in_sizes, int n_in,
                              void* d_out, int out_size, void* d_ws, size_t ws_size,
                              hipStream_t stream) {
    const float* x            = (const float*)d_in[0];  // (8,256,64,64)
    const float* bank_request = (const float*)d_in[1];  // (8,16)
    const float* style        = (const float*)d_in[2];  // (8,1,256,1,1)
    const float* bank_weight  = (const float*)d_in[3];  // (16,256,256,3,3)
    float* out = (float*)d_out;                         // (8,256,64,64)

    ushort* Ak = (ushort*)d_ws;                         // 8*9*32*256*8 elems
    ushort* xb = Ak + (size_t)8 * 9 * 32 * 256 * 8;     // 8*64*64*256 elems

    cast_x<<<dim3(HH, BB), 256, 0, stream>>>(x, xb);
    prep_filter<<<dim3(DD), 256, 0, stream>>>(bank_request, style, bank_weight, Ak);
    conv_mfma<<<dim3(512), 512, 0, stream>>>(xb, Ak, out);
}